// Round 3
// baseline (353.179 us; speedup 1.0000x reference)
//
#include <hip/hip_runtime.h>
#include <stdint.h>

#define BB 8
#define CIN 256
#define NSP 16384      // H*W
#define HID 128

typedef __bf16 bfrag __attribute__((ext_vector_type(8)));
typedef float  f32x4 __attribute__((ext_vector_type(4)));
typedef unsigned short us8 __attribute__((ext_vector_type(8)));

__device__ __forceinline__ unsigned short f2bf(float f) {
  union { float f; unsigned int u; } v; v.f = f;
  unsigned int u = v.u;
  return (unsigned short)((u + 0x7FFFu + ((u >> 16) & 1u)) >> 16);  // RNE
}

// async global->LDS, 16B per lane. LDS dest is wave-uniform base + lane*16;
// we pass per-lane ptr whose lane0 value is the wave base (t*16 layout is lane-linear).
__device__ __forceinline__ void gload_lds16(const unsigned short* g, unsigned short* l) {
  __builtin_amdgcn_global_load_lds((const __attribute__((address_space(1))) void*)g,
                                   (__attribute__((address_space(3))) void*)l, 16, 0, 0);
}

#define FENCE() asm volatile("" ::: "memory")

// ---------------- pass 0: x (fp32 [b][c][n]) -> xT (bf16 [b][n][c]); + wkvb convert; + zero ----------------
// blk < 8192: one 64c x 64n transpose tile. blk 8192..8255: wkvb rows. blk 8256: zero ctxu+sums.
__global__ __launch_bounds__(256) void la_xT(const float* __restrict__ x,
                                             unsigned short* __restrict__ xT,
                                             const float* __restrict__ w_qkv,
                                             unsigned short* __restrict__ wkvb,
                                             float* __restrict__ zbase) {
  __shared__ float Xs[64][65];
  const int blk = blockIdx.x;
  const int t = threadIdx.x;
  if (blk < 8192) {
    const int b = blk >> 10;
    const int tile = blk & 1023;
    const int c0 = (tile & 3) * 64;
    const int n0 = (tile >> 2) * 64;
    const float* xb = x + (size_t)b * CIN * NSP;
    {
      const int c = t >> 2, nf = (t & 3) * 16;
      const float* xr = xb + (size_t)(c0 + c) * NSP + n0 + nf;
#pragma unroll
      for (int i = 0; i < 4; ++i) {
        const float4 v = *(const float4*)(xr + i * 4);
        Xs[c][nf + i * 4 + 0] = v.x;
        Xs[c][nf + i * 4 + 1] = v.y;
        Xs[c][nf + i * 4 + 2] = v.z;
        Xs[c][nf + i * 4 + 3] = v.w;
      }
    }
    __syncthreads();
    {
      const int n = t >> 2, c16 = (t & 3) * 16;
      us8 v0, v1;
#pragma unroll
      for (int j = 0; j < 8; ++j) {
        v0[j] = f2bf(Xs[c16 + j][n]);
        v1[j] = f2bf(Xs[c16 + 8 + j][n]);
      }
      unsigned short* orow = xT + ((size_t)b * NSP + n0 + n) * CIN + c0 + c16;
      *(us8*)orow = v0;
      *(us8*)(orow + 8) = v1;
    }
  } else if (blk < 8256) {
    const int off = ((blk - 8192) * 256 + t) * 4;   // 0..65532
    const float4 wv4 = *(const float4*)(w_qkv + (size_t)128 * CIN + off);
    ushort4 p;
    p.x = f2bf(wv4.x); p.y = f2bf(wv4.y); p.z = f2bf(wv4.z); p.w = f2bf(wv4.w);
    *(ushort4*)(wkvb + off) = p;
  } else {
    // zero ctxu (32768 f) + sums (1024 f) contiguous = 8448 float4
    for (int i = t; i < 8448; i += 256) {
      float4 z = {0.f, 0.f, 0.f, 0.f};
      *(float4*)(zbase + i * 4) = z;
    }
  }
}

// ---------------- pass 1: k/v GEMM + exp + row-sums + context -> atomic ctxu ----------------
// Block: 128-n tile of one batch, 512 threads = 8 waves.
// B-tiles staged from xT via global_load_lds (1 dwordx4/thread/kc), 4 LDS buffers,
// chunk-XOR swizzle (pre-swizzled global src, swizzled ds_read) for conflict-free b128 reads.
// Raw s_barrier + counted vmcnt: stage(kc+2) stays in flight across the barrier.
__global__ __launch_bounds__(512, 4) void la_fused(const unsigned short* __restrict__ xT,
                                                   const unsigned short* __restrict__ wkvb,
                                                   float* __restrict__ ctxu,
                                                   float* __restrict__ sums) {
  __shared__ __align__(16) union {
    unsigned short Sx[4][4096];                                               // 4 x 8 KB staging
    struct { unsigned short Lk[64][136]; unsigned short Lv[64][136];
             float Pc[4][1024]; } e;                                          // 51200 B
  } sh;
  const int chunk = blockIdx.x;
  const int n0 = chunk * 128;
  const int b = blockIdx.y;
  const int t = threadIdx.x;
  const int lane = t & 63, wv = t >> 6;
  const int l15 = lane & 15, q = lane >> 4;
  const int qs = (q ^ ((l15 >> 1) & 3)) * 8;            // swizzled 16B-chunk offset (ushorts)
  const unsigned short* xTb = xT + ((size_t)b * NSP + n0) * CIN;
  // staging: thread t owns LDS row sn=t>>2, chunk sc8=t&3 (lane-linear dest);
  // global source chunk is the involution-swizzled one.
  const int sn = t >> 2, sc8 = t & 3;
  const int sc8s = sc8 ^ ((sn >> 1) & 3);
  const unsigned short* sg = xTb + (size_t)sn * CIN + sc8s * 8;
  unsigned short* sl = &sh.Sx[0][0] + t * 8;
  f32x4 acc[2][8];
#pragma unroll
  for (int i = 0; i < 2; ++i)
#pragma unroll
    for (int j = 0; j < 8; ++j) acc[i][j] = 0.0f;

  // prologue: stage kc=0,1
  gload_lds16(sg + 0 * 32, sl + 0 * 4096);
  gload_lds16(sg + 1 * 32, sl + 1 * 4096);
  asm volatile("s_waitcnt vmcnt(1)" ::: "memory");
  __builtin_amdgcn_s_barrier();
  FENCE();

#pragma unroll
  for (int kc = 0; kc < 6; ++kc) {
    bfrag a0 = *(const bfrag*)(wkvb + (size_t)(wv * 16 + l15) * CIN + kc * 32 + q * 8);
    bfrag a1 = *(const bfrag*)(wkvb + (size_t)(128 + wv * 16 + l15) * CIN + kc * 32 + q * 8);
    gload_lds16(sg + (kc + 2) * 32, sl + ((kc + 2) & 3) * 4096);
    const unsigned short* bufp = &sh.Sx[kc & 3][0];
#pragma unroll
    for (int ni = 0; ni < 8; ++ni) {
      bfrag bbv = *(const bfrag*)(bufp + (ni * 16 + l15) * 32 + qs);
      acc[0][ni] = __builtin_amdgcn_mfma_f32_16x16x32_bf16(a0, bbv, acc[0][ni], 0, 0, 0);
      acc[1][ni] = __builtin_amdgcn_mfma_f32_16x16x32_bf16(a1, bbv, acc[1][ni], 0, 0, 0);
    }
    asm volatile("s_waitcnt vmcnt(1)" ::: "memory");
    __builtin_amdgcn_s_barrier();
    FENCE();
  }
  {  // kc = 6 (no stage issued; must retire S7 before kc=7 reads)
    bfrag a0 = *(const bfrag*)(wkvb + (size_t)(wv * 16 + l15) * CIN + 6 * 32 + q * 8);
    bfrag a1 = *(const bfrag*)(wkvb + (size_t)(128 + wv * 16 + l15) * CIN + 6 * 32 + q * 8);
    const unsigned short* bufp = &sh.Sx[2][0];
#pragma unroll
    for (int ni = 0; ni < 8; ++ni) {
      bfrag bbv = *(const bfrag*)(bufp + (ni * 16 + l15) * 32 + qs);
      acc[0][ni] = __builtin_amdgcn_mfma_f32_16x16x32_bf16(a0, bbv, acc[0][ni], 0, 0, 0);
      acc[1][ni] = __builtin_amdgcn_mfma_f32_16x16x32_bf16(a1, bbv, acc[1][ni], 0, 0, 0);
    }
    asm volatile("s_waitcnt vmcnt(0)" ::: "memory");
    __builtin_amdgcn_s_barrier();
    FENCE();
  }
  {  // kc = 7 (final; barrier protects LDS union reuse by epilogue)
    bfrag a0 = *(const bfrag*)(wkvb + (size_t)(wv * 16 + l15) * CIN + 7 * 32 + q * 8);
    bfrag a1 = *(const bfrag*)(wkvb + (size_t)(128 + wv * 16 + l15) * CIN + 7 * 32 + q * 8);
    const unsigned short* bufp = &sh.Sx[3][0];
#pragma unroll
    for (int ni = 0; ni < 8; ++ni) {
      bfrag bbv = *(const bfrag*)(bufp + (ni * 16 + l15) * 32 + qs);
      acc[0][ni] = __builtin_amdgcn_mfma_f32_16x16x32_bf16(a0, bbv, acc[0][ni], 0, 0, 0);
      acc[1][ni] = __builtin_amdgcn_mfma_f32_16x16x32_bf16(a1, bbv, acc[1][ni], 0, 0, 0);
    }
    __builtin_amdgcn_s_barrier();
    FENCE();
  }

  // ---- exp in place on k accumulators ----
#pragma unroll
  for (int ni = 0; ni < 8; ++ni)
#pragma unroll
    for (int rg = 0; rg < 4; ++rg) acc[0][ni][rg] = __expf(acc[0][ni][rg]);

  // ---- k row-sums of exp -> atomic (unnormalized softmax denominators) ----
  {
    float sp[4] = {0.f, 0.f, 0.f, 0.f};
#pragma unroll
    for (int ni = 0; ni < 8; ++ni)
#pragma unroll
      for (int rg = 0; rg < 4; ++rg) sp[rg] += acc[0][ni][rg];
#pragma unroll
    for (int rg = 0; rg < 4; ++rg) {
      float s = sp[rg];
      s += __shfl_down(s, 8, 16);
      s += __shfl_down(s, 4, 16);
      s += __shfl_down(s, 2, 16);
      s += __shfl_down(s, 1, 16);
      if (l15 == 0) atomicAdd(&sums[b * 128 + wv * 16 + q * 4 + rg], s);
    }
  }
  // ---- context, two 64-row phases (LDS budget); combine quarters in LDS, atomicAdd to ctxu ----
#pragma unroll
  for (int ph = 0; ph < 2; ++ph) {
    if ((wv >> 2) == ph) {
      const int r = (wv & 3) * 16 + q * 4;
#pragma unroll
      for (int ni = 0; ni < 8; ++ni)
#pragma unroll
        for (int rg = 0; rg < 4; ++rg) {
          sh.e.Lk[r + rg][ni * 16 + l15] = f2bf(acc[0][ni][rg]);   // already exp'd
          sh.e.Lv[r + rg][ni * 16 + l15] = f2bf(acc[1][ni][rg]);
        }
    }
    __syncthreads();
    const int hl = wv >> 2, nq = wv & 3;
    f32x4 c2[2][2];
    c2[0][0] = 0.f; c2[0][1] = 0.f; c2[1][0] = 0.f; c2[1][1] = 0.f;
    bfrag ka[2], vb[2];
#pragma unroll
    for (int d2 = 0; d2 < 2; ++d2)
      ka[d2] = *(const bfrag*)&sh.e.Lk[hl * 32 + d2 * 16 + l15][nq * 32 + q * 8];
#pragma unroll
    for (int e2 = 0; e2 < 2; ++e2)
      vb[e2] = *(const bfrag*)&sh.e.Lv[hl * 32 + e2 * 16 + l15][nq * 32 + q * 8];
#pragma unroll
    for (int d2 = 0; d2 < 2; ++d2)
#pragma unroll
      for (int e2 = 0; e2 < 2; ++e2)
        c2[d2][e2] = __builtin_amdgcn_mfma_f32_16x16x32_bf16(ka[d2], vb[e2], c2[d2][e2], 0, 0, 0);
    const int slot = hl * 2 + (nq & 1);
    if (nq < 2) {
#pragma unroll
      for (int d2 = 0; d2 < 2; ++d2)
#pragma unroll
        for (int e2 = 0; e2 < 2; ++e2)
#pragma unroll
          for (int rg = 0; rg < 4; ++rg)
            sh.e.Pc[slot][(d2 * 16 + q * 4 + rg) * 32 + e2 * 16 + l15] = c2[d2][e2][rg];
    }
    __syncthreads();
    if (nq >= 2) {
#pragma unroll
      for (int d2 = 0; d2 < 2; ++d2)
#pragma unroll
        for (int e2 = 0; e2 < 2; ++e2)
#pragma unroll
          for (int rg = 0; rg < 4; ++rg)
            sh.e.Pc[slot][(d2 * 16 + q * 4 + rg) * 32 + e2 * 16 + l15] += c2[d2][e2][rg];
    }
    __syncthreads();
    for (int idx = t; idx < 2048; idx += 512) {
      const int h2 = idx >> 10, pos = idx & 1023;
      atomicAdd(&ctxu[(size_t)b * 4096 + (ph * 2 + h2) * 1024 + pos],
                sh.e.Pc[h2 * 2][pos] + sh.e.Pc[h2 * 2 + 1][pos]);
    }
    __syncthreads();
  }
}

// ---------------- mid: weff row (in LDS) -> wcomb row, fused ----------------
__global__ __launch_bounds__(256) void la_mid(const float* __restrict__ w_out,
                                              const float* __restrict__ ctxu,
                                              const float* __restrict__ sums,
                                              const float* __restrict__ w_qkv,
                                              unsigned short* __restrict__ wcomb) {
  __shared__ float wrow[128];
  const int o = blockIdx.x;
  const int b = blockIdx.y;
  const int t = threadIdx.x;
  if (t < 128) {
    const int h = t >> 5, d = t & 31;
    const float* wr = w_out + (size_t)o * HID + h * 32;
    const float* cr = ctxu + ((size_t)(b * 4 + h) * 32 + d) * 32;
    float s = 0.f;
#pragma unroll 8
    for (int e = 0; e < 32; ++e) s += wr[e] * cr[e];
    wrow[t] = s * (1.0f / sums[b * 128 + t]);
  }
  __syncthreads();
  float s = 0.f;
#pragma unroll 8
  for (int hd = 0; hd < 128; ++hd) s += wrow[hd] * w_qkv[(size_t)hd * CIN + t];
  wcomb[((size_t)b * 256 + o) * 256 + t] = f2bf(s);
}

// ---------------- out[b][o][n] = sum_c Wcomb[b][o][c] * xT-gemm + b_out[o] ----------------
// Same staged-from-xT structure as la_fused. M=256, N=128, 8 waves (64m x 64n).
__global__ __launch_bounds__(512, 4) void la_out(const unsigned short* __restrict__ wcomb,
                                                 const unsigned short* __restrict__ xT,
                                                 const float* __restrict__ b_out,
                                                 float* __restrict__ out) {
  __shared__ __align__(16) unsigned short Sx[4][4096];
  const int n0 = blockIdx.x * 128;
  const int b = blockIdx.y;
  const int t = threadIdx.x;
  const int lane = t & 63, wv = t >> 6;
  const int l15 = lane & 15, q = lane >> 4;
  const int qs = (q ^ ((l15 >> 1) & 3)) * 8;
  const int wm = (wv & 3) * 64;
  const int wn = (wv >> 2) * 64;
  const unsigned short* xTb = xT + ((size_t)b * NSP + n0) * CIN;
  const unsigned short* abase = wcomb + (size_t)b * 256 * 256;
  const int sn = t >> 2, sc8 = t & 3;
  const int sc8s = sc8 ^ ((sn >> 1) & 3);
  const unsigned short* sg = xTb + (size_t)sn * CIN + sc8s * 8;
  unsigned short* sl = &Sx[0][0] + t * 8;
  f32x4 acc[4][4];
#pragma unroll
  for (int i = 0; i < 4; ++i)
#pragma unroll
    for (int j = 0; j < 4; ++j) acc[i][j] = 0.0f;

  gload_lds16(sg + 0 * 32, sl + 0 * 4096);
  gload_lds16(sg + 1 * 32, sl + 1 * 4096);
  asm volatile("s_waitcnt vmcnt(1)" ::: "memory");
  __builtin_amdgcn_s_barrier();
  FENCE();

#pragma unroll
  for (int kc = 0; kc < 6; ++kc) {
    bfrag a[4];
#pragma unroll
    for (int mi = 0; mi < 4; ++mi)
      a[mi] = *(const bfrag*)(abase + (size_t)(wm + mi * 16 + l15) * 256 + kc * 32 + q * 8);
    gload_lds16(sg + (kc + 2) * 32, sl + ((kc + 2) & 3) * 4096);
    const unsigned short* bufp = &Sx[kc & 3][0];
#pragma unroll
    for (int ni = 0; ni < 4; ++ni) {
      bfrag bbv = *(const bfrag*)(bufp + (wn + ni * 16 + l15) * 32 + qs);
#pragma unroll
      for (int mi = 0; mi < 4; ++mi)
        acc[mi][ni] = __builtin_amdgcn_mfma_f32_16x16x32_bf16(a[mi], bbv, acc[mi][ni], 0, 0, 0);
    }
    asm volatile("s_waitcnt vmcnt(1)" ::: "memory");
    __builtin_amdgcn_s_barrier();
    FENCE();
  }
  {  // kc = 6
    bfrag a[4];
#pragma unroll
    for (int mi = 0; mi < 4; ++mi)
      a[mi] = *(const bfrag*)(abase + (size_t)(wm + mi * 16 + l15) * 256 + 6 * 32 + q * 8);
    const unsigned short* bufp = &Sx[2][0];
#pragma unroll
    for (int ni = 0; ni < 4; ++ni) {
      bfrag bbv = *(const bfrag*)(bufp + (wn + ni * 16 + l15) * 32 + qs);
#pragma unroll
      for (int mi = 0; mi < 4; ++mi)
        acc[mi][ni] = __builtin_amdgcn_mfma_f32_16x16x32_bf16(a[mi], bbv, acc[mi][ni], 0, 0, 0);
    }
    asm volatile("s_waitcnt vmcnt(0)" ::: "memory");
    __builtin_amdgcn_s_barrier();
    FENCE();
  }
  {  // kc = 7 (no trailing barrier needed: epilogue is global stores only)
    bfrag a[4];
#pragma unroll
    for (int mi = 0; mi < 4; ++mi)
      a[mi] = *(const bfrag*)(abase + (size_t)(wm + mi * 16 + l15) * 256 + 7 * 32 + q * 8);
    const unsigned short* bufp = &Sx[3][0];
#pragma unroll
    for (int ni = 0; ni < 4; ++ni) {
      bfrag bbv = *(const bfrag*)(bufp + (wn + ni * 16 + l15) * 32 + qs);
#pragma unroll
      for (int mi = 0; mi < 4; ++mi)
        acc[mi][ni] = __builtin_amdgcn_mfma_f32_16x16x32_bf16(a[mi], bbv, acc[mi][ni], 0, 0, 0);
    }
  }
  float* obase = out + (size_t)b * 256 * NSP;
#pragma unroll
  for (int mi = 0; mi < 4; ++mi) {
    const int ob = wm + mi * 16 + q * 4;
    const float4 bias = *(const float4*)(b_out + ob);
    float ba[4] = {bias.x, bias.y, bias.z, bias.w};
#pragma unroll
    for (int ni = 0; ni < 4; ++ni) {
      const int n = n0 + wn + ni * 16 + l15;
#pragma unroll
      for (int rg = 0; rg < 4; ++rg)
        obase[(size_t)(ob + rg) * NSP + n] = acc[mi][ni][rg] + ba[rg];
    }
  }
}

// ---------------- workspace layout ----------------
// xT    : 0        , 67108864 B  (B*N*C bf16, transposed x)
// wkvb  : 67108864 , 131072 B    (256x256 bf16 k/v weights)
// ctxu  : 67239936 , 131072 B    (fp32, zeroed by la_xT)
// sums  : 67371008 , 4096 B      (fp32, zeroed by la_xT; contiguous with ctxu)
// wcomb : 67375104 , 1048576 B   (bf16)
// total ~65.3 MB

extern "C" void kernel_launch(void* const* d_in, const int* in_sizes, int n_in,
                              void* d_out, int out_size, void* d_ws, size_t ws_size,
                              hipStream_t stream) {
  (void)in_sizes; (void)n_in; (void)out_size; (void)ws_size;
  const float* x     = (const float*)d_in[0];
  const float* w_qkv = (const float*)d_in[1];
  const float* w_out = (const float*)d_in[2];
  const float* b_out = (const float*)d_in[3];
  float* out = (float*)d_out;
  char* ws = (char*)d_ws;
  unsigned short* xTws  = (unsigned short*)(ws);
  unsigned short* wkvb  = (unsigned short*)(ws + 67108864);
  float* ctxu           = (float*)(ws + 67239936);
  float* sums           = (float*)(ws + 67371008);
  unsigned short* wcomb = (unsigned short*)(ws + 67375104);

  la_xT<<<dim3(8257), dim3(256), 0, stream>>>(x, xTws, w_qkv, wkvb, ctxu);
  la_fused<<<dim3(NSP / 128, BB), dim3(512), 0, stream>>>(xTws, wkvb, ctxu, sums);
  la_mid<<<dim3(256, BB), dim3(256), 0, stream>>>(w_out, ctxu, sums, w_qkv, wcomb);
  la_out<<<dim3(NSP / 128, BB), dim3(512), 0, stream>>>(wcomb, xTws, b_out, out);
}